// Round 10
// baseline (49257.068 us; speedup 1.0000x reference)
//
#include <hip/hip_runtime.h>
#include <stdint.h>

// CharLSTM persistent-RNN kernel for MI355X. f32 in / f32 out.
// R9:  conflict-free fragment layout; tagged 64-bit h words (f32<<32 | step).
// R10: flag hierarchy: -6.5% -> dependent hop, refuted.
// R11: single-hop polling + x-dot overlap: neutral.
// R12: float4 fragments, ds_read_b128, DPP reduce: -3%.
// R13: s_sleep(2) poll backoff + coalesced single-line publish: -41% (43.2ms).
// R14: 1024-thr shape: disaster (spill->HBM). Shape pinned 512thr.
// R15: sc0-only asm polls: hang risk. Sync loads only via __hip_atomic_load.
// R16: relay broadcast: WORSE (+19ms). Request rate not the binding lever.
// R17: register pinning: dur identical -> weight re-fetch hides under slack.
// R19: dual-set pipelined poll: +7.5% -> compiler vmcnt(0) kills the stagger;
//      cadence not improvable at intrinsic level; extra pressure mildly hurts.
// R20: producer-path + poll-thinning, on R13's chassis:
//      (a) LAST-ARRIVER PUBLISH: barrier B deleted. lane0 of each wave writes
//          hn to parity-dbuf hout[2][8] + bumps a monotonic LDS counter
//          (acq_rel); the 8th arriver's own wave stores the 64B line
//          immediately (lanes 0-7, coalesced). Publish starts the cycle the
//          slowest gate finishes -- no barrier release + wave0 wakeup.
//      (b) PHASE-AWARE POLL: on first miss, one coarse s_sleep(16) (~1024cyc,
//          inside the >=3000cyc dead window), then R13's s_sleep(2) cadence.
//          Removes ~8-10 wasted LLC poll rounds/step (R19 showed nonzero cost).

#define T_STEPS 16384
#define HID     2048
#define EMBD    512
#define NCH     128
#define FANIN   (EMBD + HID)
#define NBLK    256
#define TPB     512
#define NEUR_PER_WG 8

static_assert(TPB == EMBD, "index math assumes TPB == EMBD");
static_assert(NBLK * NEUR_PER_WG == HID, "neuron coverage");

__device__ __forceinline__ float sigmoid_f(float x) {
  return 1.0f / (1.0f + __expf(-x));
}
__device__ __forceinline__ float tanh_f(float x) {
  return 1.0f - 2.0f / (__expf(2.0f * x) + 1.0f);
}
__device__ __forceinline__ unsigned long long ld_agent64(const unsigned long long* p) {
  return __hip_atomic_load(p, __ATOMIC_RELAXED, __HIP_MEMORY_SCOPE_AGENT);
}
__device__ __forceinline__ void st_agent64(unsigned long long* p, unsigned long long v) {
  __hip_atomic_store(p, v, __ATOMIC_RELAXED, __HIP_MEMORY_SCOPE_AGENT);
}

// ---- VALU-only wave64 reduction: DPP row_shr tree + readlane of row tails ----
#define DPP_ROW_SHR(n) (0x110 | (n))
__device__ __forceinline__ float row_reduce(float x) {
  x += __int_as_float(__builtin_amdgcn_update_dpp(0, __float_as_int(x), DPP_ROW_SHR(1), 0xF, 0xF, true));
  x += __int_as_float(__builtin_amdgcn_update_dpp(0, __float_as_int(x), DPP_ROW_SHR(2), 0xF, 0xF, true));
  x += __int_as_float(__builtin_amdgcn_update_dpp(0, __float_as_int(x), DPP_ROW_SHR(4), 0xF, 0xF, true));
  x += __int_as_float(__builtin_amdgcn_update_dpp(0, __float_as_int(x), DPP_ROW_SHR(8), 0xF, 0xF, true));
  return x;  // lanes 15/31/47/63 hold their row's sum
}
__device__ __forceinline__ float wave_sum(float x) {
  const int xi = __float_as_int(row_reduce(x));
  return __int_as_float(__builtin_amdgcn_readlane(xi, 15))
       + __int_as_float(__builtin_amdgcn_readlane(xi, 31))
       + __int_as_float(__builtin_amdgcn_readlane(xi, 47))
       + __int_as_float(__builtin_amdgcn_readlane(xi, 63));
}

__global__ __launch_bounds__(TPB, 2) void lstm_persist(
    const int* __restrict__ seq,
    const float* __restrict__ emb,
    const float* __restrict__ Wf, const float* __restrict__ bfv,
    const float* __restrict__ Wi, const float* __restrict__ biv,
    const float* __restrict__ Wg, const float* __restrict__ bgv,
    const float* __restrict__ Wo, const float* __restrict__ bov,
    const float* __restrict__ Wfc, const float* __restrict__ bfc,
    unsigned long long* __restrict__ hbuf,   // [2][HID] tagged h
    float* __restrict__ out)                 // f32: [T][NCH] logits, h[HID], c[HID]
{
  __shared__ __attribute__((aligned(16))) float h_lds[2][HID];
  __shared__ float hout[2][NEUR_PER_WG];   // parity-dbuf collected outputs
  __shared__ int s_cnt;                    // monotonic publish counter

  const int tid  = threadIdx.x;
  const int wv   = tid >> 6;
  const int lane = tid & 63;
  const int j    = blockIdx.x * NEUR_PER_WG + wv;   // neuron this wave owns

  if (tid == 0) s_cnt = 0;

  // seq dtype guard (selects int32 on this data; kept for safety)
  int shift = 1;
  for (int k = 0; k < 64; ++k) {
    if (seq[2 * k + 1] != 0) { shift = 0; break; }
  }

  // ---- preload weights, float4 chunks: lane l owns cols {256k+4l..+3} ----
  const float* Wmat[4] = {Wf, Wi, Wg, Wo};
  const float* bvec[4] = {bfv, biv, bgv, bov};
  float4 wh4[4][8], wx4[4][2];
  float  bias[4];
  #pragma unroll
  for (int g = 0; g < 4; ++g) {
    const float* rp = Wmat[g] + (size_t)j * FANIN;
    const float4* hp4 = reinterpret_cast<const float4*>(rp + EMBD);
    const float4* xp4 = reinterpret_cast<const float4*>(rp);
    #pragma unroll
    for (int k = 0; k < 8; ++k) wh4[g][k] = hp4[k * 64 + lane];
    #pragma unroll
    for (int k = 0; k < 2; ++k) wx4[g][k] = xp4[k * 64 + lane];
    bias[g] = bvec[g][j];
  }

  // ---- logits duty: even WGs' wave 1 each own one output column ----
  int lcol = -1;
  float4 wfc4[8];
  float bfc_c = 0.0f;
  if (((blockIdx.x & 1) == 0) && wv == 1) {
    lcol = blockIdx.x >> 1;                 // 0..127
    const float4* wp4 = reinterpret_cast<const float4*>(Wfc + (size_t)lcol * HID);
    #pragma unroll
    for (int u = 0; u < 8; ++u) wfc4[u] = wp4[u * 64 + lane];
    bfc_c = bfc[lcol];
  }

  __syncthreads();   // s_cnt init visible

  float creg = 0.0f;  // cell state (lane 0 only)
  const int i0 = tid, i1 = tid + TPB, i2 = tid + 2 * TPB, i3 = tid + 3 * TPB;

  for (int t = 0; t < T_STEPS; ++t) {
    const int bsel = t & 1;
    const unsigned long long* src = hbuf + (size_t)bsel * HID;
    const unsigned ut = (unsigned)t;

    // ---- issue the 4 tagged h loads first (outstanding during x work) ----
    unsigned long long v0 = ld_agent64(src + i0), v1 = ld_agent64(src + i1),
                       v2 = ld_agent64(src + i2), v3 = ld_agent64(src + i3);

    // ---- x loads (L2-resident emb row, float4 coalesced) ----
    const int s = seq[(size_t)t << shift];
    const float4* xr4 = reinterpret_cast<const float4*>(emb + (size_t)s * EMBD);
    const float4 xv0 = xr4[lane];
    const float4 xv1 = xr4[64 + lane];

    // ---- x-part of the gate dots: independent of h, hides h latency ----
    float a0 = 0.0f, a1 = 0.0f, a2 = 0.0f, a3 = 0.0f;
    #pragma unroll
    for (int k = 0; k < 2; ++k) {
      const float4 xv = (k == 0) ? xv0 : xv1;
      a0 = fmaf(wx4[0][k].x, xv.x, a0); a0 = fmaf(wx4[0][k].y, xv.y, a0);
      a0 = fmaf(wx4[0][k].z, xv.z, a0); a0 = fmaf(wx4[0][k].w, xv.w, a0);
      a1 = fmaf(wx4[1][k].x, xv.x, a1); a1 = fmaf(wx4[1][k].y, xv.y, a1);
      a1 = fmaf(wx4[1][k].z, xv.z, a1); a1 = fmaf(wx4[1][k].w, xv.w, a1);
      a2 = fmaf(wx4[2][k].x, xv.x, a2); a2 = fmaf(wx4[2][k].y, xv.y, a2);
      a2 = fmaf(wx4[2][k].z, xv.z, a2); a2 = fmaf(wx4[2][k].w, xv.w, a2);
      a3 = fmaf(wx4[3][k].x, xv.x, a3); a3 = fmaf(wx4[3][k].y, xv.y, a3);
      a3 = fmaf(wx4[3][k].z, xv.z, a3); a3 = fmaf(wx4[3][k].w, xv.w, a3);
    }

    // ---- phase-aware poll: coarse sleep through the dead window, then fine ----
    if (((unsigned)v0 != ut) | ((unsigned)v1 != ut) |
        ((unsigned)v2 != ut) | ((unsigned)v3 != ut)) {
      __builtin_amdgcn_s_sleep(16);   // ~1024 cyc: data can't be ready yet
      do {
        if ((unsigned)v0 != ut) v0 = ld_agent64(src + i0);
        if ((unsigned)v1 != ut) v1 = ld_agent64(src + i1);
        if ((unsigned)v2 != ut) v2 = ld_agent64(src + i2);
        if ((unsigned)v3 != ut) v3 = ld_agent64(src + i3);
        if (((unsigned)v0 == ut) & ((unsigned)v1 == ut) &
            ((unsigned)v2 == ut) & ((unsigned)v3 == ut)) break;
        __builtin_amdgcn_s_sleep(2);  // R13 cadence near arrival
      } while (true);
    }
    h_lds[bsel][i0] = __uint_as_float((unsigned)(v0 >> 32));
    h_lds[bsel][i1] = __uint_as_float((unsigned)(v1 >> 32));
    h_lds[bsel][i2] = __uint_as_float((unsigned)(v2 >> 32));
    h_lds[bsel][i3] = __uint_as_float((unsigned)(v3 >> 32));
    __syncthreads();   // barrier A: h_lds complete

    // ---- h-part of the gate dots: 8x ds_read_b128, conflict-free ----
    const float4* hp4 = reinterpret_cast<const float4*>(&h_lds[bsel][0]);
    #pragma unroll
    for (int k = 0; k < 8; ++k) {
      const float4 hv = hp4[k * 64 + lane];
      a0 = fmaf(wh4[0][k].x, hv.x, a0); a0 = fmaf(wh4[0][k].y, hv.y, a0);
      a0 = fmaf(wh4[0][k].z, hv.z, a0); a0 = fmaf(wh4[0][k].w, hv.w, a0);
      a1 = fmaf(wh4[1][k].x, hv.x, a1); a1 = fmaf(wh4[1][k].y, hv.y, a1);
      a1 = fmaf(wh4[1][k].z, hv.z, a1); a1 = fmaf(wh4[1][k].w, hv.w, a1);
      a2 = fmaf(wh4[2][k].x, hv.x, a2); a2 = fmaf(wh4[2][k].y, hv.y, a2);
      a2 = fmaf(wh4[2][k].z, hv.z, a2); a2 = fmaf(wh4[2][k].w, hv.w, a2);
      a3 = fmaf(wh4[3][k].x, hv.x, a3); a3 = fmaf(wh4[3][k].y, hv.y, a3);
      a3 = fmaf(wh4[3][k].z, hv.z, a3); a3 = fmaf(wh4[3][k].w, hv.w, a3);
    }

    // ---- VALU-only reduction (no DS-pipe shfl) ----
    const float A0 = wave_sum(a0);
    const float A1 = wave_sum(a1);
    const float A2 = wave_sum(a2);
    const float A3 = wave_sum(a3);

    // ---- gates + last-arriver detection (no barrier B) ----
    int amlast = 0;
    if (lane == 0) {
      const float fg = sigmoid_f(A0 + bias[0]);
      const float ig = sigmoid_f(A1 + bias[1]);
      const float gg = tanh_f(A2 + bias[2]);
      const float og = sigmoid_f(A3 + bias[3]);
      creg = fg * creg + ig * gg;
      const float hn = og * tanh_f(creg);
      hout[bsel][wv] = hn;
      const int old = __hip_atomic_fetch_add(&s_cnt, 1, __ATOMIC_ACQ_REL,
                                             __HIP_MEMORY_SCOPE_WORKGROUP);
      amlast = (old == 8 * t + 7);
      if (t == T_STEPS - 1) {
        out[(size_t)T_STEPS * NCH + j]       = hn;     // final h
        out[(size_t)T_STEPS * NCH + HID + j] = creg;   // final c
      }
    }
    amlast = __shfl(amlast, 0, 64);

    // ---- publish by the last arriver's wave: ONE coalesced 64B line ----
    if (amlast && lane < NEUR_PER_WG) {
      const unsigned long long pk =
          ((unsigned long long)__float_as_uint(hout[bsel][lane]) << 32) |
          (unsigned long long)(unsigned)(t + 1);
      st_agent64(&hbuf[(size_t)((t + 1) & 1) * HID +
                       (size_t)blockIdx.x * NEUR_PER_WG + lane], pk);
    }

    // ---- logits for step t-1 from already-staged h[t] (rides in wait slack) ----
    if (lcol >= 0 && t > 0) {
      const float4* hq4 = reinterpret_cast<const float4*>(&h_lds[bsel][0]);
      float sacc = 0.0f;
      #pragma unroll
      for (int u = 0; u < 8; ++u) {
        const float4 hv = hq4[u * 64 + lane];
        sacc = fmaf(wfc4[u].x, hv.x, sacc); sacc = fmaf(wfc4[u].y, hv.y, sacc);
        sacc = fmaf(wfc4[u].z, hv.z, sacc); sacc = fmaf(wfc4[u].w, hv.w, sacc);
      }
      const float S = wave_sum(sacc);
      if (lane == 0) out[(size_t)(t - 1) * NCH + lcol] = S + bfc_c;
    }
  }

  // ---- epilogue: stage h[T] (tag T, slot 0) and emit logits for t = T-1 ----
  {
    const unsigned long long* src = hbuf;  // T_STEPS & 1 == 0
    const unsigned ut = (unsigned)T_STEPS;
    unsigned long long v0 = ld_agent64(src + i0), v1 = ld_agent64(src + i1),
                       v2 = ld_agent64(src + i2), v3 = ld_agent64(src + i3);
    while (((unsigned)v0 != ut) | ((unsigned)v1 != ut) |
           ((unsigned)v2 != ut) | ((unsigned)v3 != ut)) {
      __builtin_amdgcn_s_sleep(2);
      if ((unsigned)v0 != ut) v0 = ld_agent64(src + i0);
      if ((unsigned)v1 != ut) v1 = ld_agent64(src + i1);
      if ((unsigned)v2 != ut) v2 = ld_agent64(src + i2);
      if ((unsigned)v3 != ut) v3 = ld_agent64(src + i3);
    }
    h_lds[0][i0] = __uint_as_float((unsigned)(v0 >> 32));
    h_lds[0][i1] = __uint_as_float((unsigned)(v1 >> 32));
    h_lds[0][i2] = __uint_as_float((unsigned)(v2 >> 32));
    h_lds[0][i3] = __uint_as_float((unsigned)(v3 >> 32));
    __syncthreads();
    if (lcol >= 0) {
      const float4* hq4 = reinterpret_cast<const float4*>(&h_lds[0][0]);
      float sacc = 0.0f;
      #pragma unroll
      for (int u = 0; u < 8; ++u) {
        const float4 hv = hq4[u * 64 + lane];
        sacc = fmaf(wfc4[u].x, hv.x, sacc); sacc = fmaf(wfc4[u].y, hv.y, sacc);
        sacc = fmaf(wfc4[u].z, hv.z, sacc); sacc = fmaf(wfc4[u].w, hv.w, sacc);
      }
      const float S = wave_sum(sacc);
      if (lane == 0) out[(size_t)(T_STEPS - 1) * NCH + lcol] = S + bfc_c;
    }
  }
}

extern "C" void kernel_launch(void* const* d_in, const int* in_sizes, int n_in,
                              void* d_out, int out_size, void* d_ws, size_t ws_size,
                              hipStream_t stream) {
  (void)in_sizes; (void)n_in; (void)out_size; (void)ws_size;
  const int* seq     = (const int*)d_in[0];
  const float* emb   = (const float*)d_in[1];
  const float* Wf    = (const float*)d_in[2];
  const float* bfv   = (const float*)d_in[3];
  const float* Wi    = (const float*)d_in[4];
  const float* biv   = (const float*)d_in[5];
  const float* Wg    = (const float*)d_in[6];
  const float* bgv   = (const float*)d_in[7];
  const float* Wo    = (const float*)d_in[8];
  const float* bov   = (const float*)d_in[9];
  const float* Wfc   = (const float*)d_in[10];
  const float* bfc   = (const float*)d_in[11];
  float* out         = (float*)d_out;
  unsigned long long* hbuf = (unsigned long long*)d_ws;   // 2*HID*8 = 32 KB

  hipMemsetAsync(d_ws, 0, 2 * HID * sizeof(unsigned long long), stream);

  void* args[] = {
    (void*)&seq, (void*)&emb,
    (void*)&Wf, (void*)&bfv, (void*)&Wi, (void*)&biv,
    (void*)&Wg, (void*)&bgv, (void*)&Wo, (void*)&bov,
    (void*)&Wfc, (void*)&bfc,
    (void*)&hbuf, (void*)&out
  };
  hipLaunchCooperativeKernel((const void*)lstm_persist, dim3(NBLK), dim3(TPB),
                             args, 0, stream);
}

// Round 11
// 43140.967 us; speedup vs baseline: 1.1418x; 1.1418x over previous
//
#include <hip/hip_runtime.h>
#include <stdint.h>

// CharLSTM persistent-RNN kernel for MI355X. f32 in / f32 out.
// R9:  conflict-free fragment layout; tagged 64-bit h words (f32<<32 | step).
// R10: flag hierarchy: -6.5% -> dependent hop, refuted.
// R11: single-hop polling + x-dot overlap: neutral.
// R12: float4 fragments, ds_read_b128, DPP reduce: -3%.
// R13: s_sleep(2) poll backoff + coalesced single-line publish: -41% (43.2ms).
// R14: 1024-thr shape: disaster (spill->HBM). Shape pinned 512thr, lb(512,2).
// R15: sc0-only asm polls: hang risk. Sync loads/stores only via HIP atomics.
// R16: relay broadcast: WORSE (+19ms) -- but taught that per-hop cost is
//      ~3000cyc REGARDLESS of poller count (8 relays tight-spinning saw the
//      same round latency as 256 WGs).
// R17: register pinning: dur identical -> weight re-fetch hides under slack.
// R19: dual-set pipelined poll: +7.5% -> extra pressure, no cadence gain.
// R20: coarse-sleep + last-arriver publish: +14% -> data arrives within
//      ~1000cyc of first check; both reverted.
// R21: cycle accounting says R13's 6330cyc step hides ~2000-2500cyc PER POLL
//      ROUND -- consistent with the publish store retiring DIRTY in the
//      producer XCD's L2 (relaxed agent store), so every consumer poll pays
//      a cross-XCD dirty-snoop (consumer -> LLC -> owner L2 -> back).
//      Single-variable fix: publish with SYSTEM scope -> store pushes through
//      to the system coherence point (LLC); consumer polls become clean LLC
//      hits (~700cyc). Everything else is R13 verbatim.

#define T_STEPS 16384
#define HID     2048
#define EMBD    512
#define NCH     128
#define FANIN   (EMBD + HID)
#define NBLK    256
#define TPB     512
#define NEUR_PER_WG 8

static_assert(TPB == EMBD, "index math assumes TPB == EMBD");
static_assert(NBLK * NEUR_PER_WG == HID, "neuron coverage");

__device__ __forceinline__ float sigmoid_f(float x) {
  return 1.0f / (1.0f + __expf(-x));
}
__device__ __forceinline__ float tanh_f(float x) {
  return 1.0f - 2.0f / (__expf(2.0f * x) + 1.0f);
}
__device__ __forceinline__ unsigned long long ld_agent64(const unsigned long long* p) {
  return __hip_atomic_load(p, __ATOMIC_RELAXED, __HIP_MEMORY_SCOPE_AGENT);
}
// SYSTEM-scope publish: write through to the system coherence point so the
// line is CLEAN in LLC when consumers poll (no cross-XCD dirty snoop).
__device__ __forceinline__ void st_sys64(unsigned long long* p, unsigned long long v) {
  __hip_atomic_store(p, v, __ATOMIC_RELAXED, __HIP_MEMORY_SCOPE_SYSTEM);
}

// ---- VALU-only wave64 reduction: DPP row_shr tree + readlane of row tails ----
#define DPP_ROW_SHR(n) (0x110 | (n))
__device__ __forceinline__ float row_reduce(float x) {
  x += __int_as_float(__builtin_amdgcn_update_dpp(0, __float_as_int(x), DPP_ROW_SHR(1), 0xF, 0xF, true));
  x += __int_as_float(__builtin_amdgcn_update_dpp(0, __float_as_int(x), DPP_ROW_SHR(2), 0xF, 0xF, true));
  x += __int_as_float(__builtin_amdgcn_update_dpp(0, __float_as_int(x), DPP_ROW_SHR(4), 0xF, 0xF, true));
  x += __int_as_float(__builtin_amdgcn_update_dpp(0, __float_as_int(x), DPP_ROW_SHR(8), 0xF, 0xF, true));
  return x;  // lanes 15/31/47/63 hold their row's sum
}
__device__ __forceinline__ float wave_sum(float x) {
  const int xi = __float_as_int(row_reduce(x));
  return __int_as_float(__builtin_amdgcn_readlane(xi, 15))
       + __int_as_float(__builtin_amdgcn_readlane(xi, 31))
       + __int_as_float(__builtin_amdgcn_readlane(xi, 47))
       + __int_as_float(__builtin_amdgcn_readlane(xi, 63));
}

__global__ __launch_bounds__(TPB, 2) void lstm_persist(
    const int* __restrict__ seq,
    const float* __restrict__ emb,
    const float* __restrict__ Wf, const float* __restrict__ bfv,
    const float* __restrict__ Wi, const float* __restrict__ biv,
    const float* __restrict__ Wg, const float* __restrict__ bgv,
    const float* __restrict__ Wo, const float* __restrict__ bov,
    const float* __restrict__ Wfc, const float* __restrict__ bfc,
    unsigned long long* __restrict__ hbuf,   // [2][HID] tagged h
    float* __restrict__ out)                 // f32: [T][NCH] logits, h[HID], c[HID]
{
  __shared__ __attribute__((aligned(16))) float h_lds[2][HID];
  __shared__ float hout[NEUR_PER_WG];   // per-step collected neuron outputs

  const int tid  = threadIdx.x;
  const int wv   = tid >> 6;
  const int lane = tid & 63;
  const int j    = blockIdx.x * NEUR_PER_WG + wv;   // neuron this wave owns

  // seq dtype guard (selects int32 on this data; kept for safety)
  int shift = 1;
  for (int k = 0; k < 64; ++k) {
    if (seq[2 * k + 1] != 0) { shift = 0; break; }
  }

  // ---- preload weights, float4 chunks: lane l owns cols {256k+4l..+3} ----
  const float* Wmat[4] = {Wf, Wi, Wg, Wo};
  const float* bvec[4] = {bfv, biv, bgv, bov};
  float4 wh4[4][8], wx4[4][2];
  float  bias[4];
  #pragma unroll
  for (int g = 0; g < 4; ++g) {
    const float* rp = Wmat[g] + (size_t)j * FANIN;
    const float4* hp4 = reinterpret_cast<const float4*>(rp + EMBD);
    const float4* xp4 = reinterpret_cast<const float4*>(rp);
    #pragma unroll
    for (int k = 0; k < 8; ++k) wh4[g][k] = hp4[k * 64 + lane];
    #pragma unroll
    for (int k = 0; k < 2; ++k) wx4[g][k] = xp4[k * 64 + lane];
    bias[g] = bvec[g][j];
  }

  // ---- logits duty: even WGs' wave 1 each own one output column ----
  int lcol = -1;
  float4 wfc4[8];
  float bfc_c = 0.0f;
  if (((blockIdx.x & 1) == 0) && wv == 1) {
    lcol = blockIdx.x >> 1;                 // 0..127
    const float4* wp4 = reinterpret_cast<const float4*>(Wfc + (size_t)lcol * HID);
    #pragma unroll
    for (int u = 0; u < 8; ++u) wfc4[u] = wp4[u * 64 + lane];
    bfc_c = bfc[lcol];
  }

  float creg = 0.0f;  // cell state (lane 0 only)
  const int i0 = tid, i1 = tid + TPB, i2 = tid + 2 * TPB, i3 = tid + 3 * TPB;

  for (int t = 0; t < T_STEPS; ++t) {
    const int bsel = t & 1;
    const unsigned long long* src = hbuf + (size_t)bsel * HID;
    const unsigned ut = (unsigned)t;

    // ---- issue the 4 tagged h loads first (outstanding during x work) ----
    unsigned long long v0 = ld_agent64(src + i0), v1 = ld_agent64(src + i1),
                       v2 = ld_agent64(src + i2), v3 = ld_agent64(src + i3);

    // ---- x loads (L2-resident emb row, float4 coalesced) ----
    const int s = seq[(size_t)t << shift];
    const float4* xr4 = reinterpret_cast<const float4*>(emb + (size_t)s * EMBD);
    const float4 xv0 = xr4[lane];
    const float4 xv1 = xr4[64 + lane];

    // ---- x-part of the gate dots: independent of h, hides h latency ----
    float a0 = 0.0f, a1 = 0.0f, a2 = 0.0f, a3 = 0.0f;
    #pragma unroll
    for (int k = 0; k < 2; ++k) {
      const float4 xv = (k == 0) ? xv0 : xv1;
      a0 = fmaf(wx4[0][k].x, xv.x, a0); a0 = fmaf(wx4[0][k].y, xv.y, a0);
      a0 = fmaf(wx4[0][k].z, xv.z, a0); a0 = fmaf(wx4[0][k].w, xv.w, a0);
      a1 = fmaf(wx4[1][k].x, xv.x, a1); a1 = fmaf(wx4[1][k].y, xv.y, a1);
      a1 = fmaf(wx4[1][k].z, xv.z, a1); a1 = fmaf(wx4[1][k].w, xv.w, a1);
      a2 = fmaf(wx4[2][k].x, xv.x, a2); a2 = fmaf(wx4[2][k].y, xv.y, a2);
      a2 = fmaf(wx4[2][k].z, xv.z, a2); a2 = fmaf(wx4[2][k].w, xv.w, a2);
      a3 = fmaf(wx4[3][k].x, xv.x, a3); a3 = fmaf(wx4[3][k].y, xv.y, a3);
      a3 = fmaf(wx4[3][k].z, xv.z, a3); a3 = fmaf(wx4[3][k].w, xv.w, a3);
    }

    // ---- single-hop readiness with s_sleep backoff (R13 verbatim) ----
    while (((unsigned)v0 != ut) | ((unsigned)v1 != ut) |
           ((unsigned)v2 != ut) | ((unsigned)v3 != ut)) {
      __builtin_amdgcn_s_sleep(2);   // keep per-line request rate low
      if ((unsigned)v0 != ut) v0 = ld_agent64(src + i0);
      if ((unsigned)v1 != ut) v1 = ld_agent64(src + i1);
      if ((unsigned)v2 != ut) v2 = ld_agent64(src + i2);
      if ((unsigned)v3 != ut) v3 = ld_agent64(src + i3);
    }
    h_lds[bsel][i0] = __uint_as_float((unsigned)(v0 >> 32));
    h_lds[bsel][i1] = __uint_as_float((unsigned)(v1 >> 32));
    h_lds[bsel][i2] = __uint_as_float((unsigned)(v2 >> 32));
    h_lds[bsel][i3] = __uint_as_float((unsigned)(v3 >> 32));
    __syncthreads();

    // ---- h-part of the gate dots: 8x ds_read_b128, conflict-free ----
    const float4* hp4 = reinterpret_cast<const float4*>(&h_lds[bsel][0]);
    #pragma unroll
    for (int k = 0; k < 8; ++k) {
      const float4 hv = hp4[k * 64 + lane];
      a0 = fmaf(wh4[0][k].x, hv.x, a0); a0 = fmaf(wh4[0][k].y, hv.y, a0);
      a0 = fmaf(wh4[0][k].z, hv.z, a0); a0 = fmaf(wh4[0][k].w, hv.w, a0);
      a1 = fmaf(wh4[1][k].x, hv.x, a1); a1 = fmaf(wh4[1][k].y, hv.y, a1);
      a1 = fmaf(wh4[1][k].z, hv.z, a1); a1 = fmaf(wh4[1][k].w, hv.w, a1);
      a2 = fmaf(wh4[2][k].x, hv.x, a2); a2 = fmaf(wh4[2][k].y, hv.y, a2);
      a2 = fmaf(wh4[2][k].z, hv.z, a2); a2 = fmaf(wh4[2][k].w, hv.w, a2);
      a3 = fmaf(wh4[3][k].x, hv.x, a3); a3 = fmaf(wh4[3][k].y, hv.y, a3);
      a3 = fmaf(wh4[3][k].z, hv.z, a3); a3 = fmaf(wh4[3][k].w, hv.w, a3);
    }

    // ---- VALU-only reduction (no DS-pipe shfl) ----
    const float A0 = wave_sum(a0);
    const float A1 = wave_sum(a1);
    const float A2 = wave_sum(a2);
    const float A3 = wave_sum(a3);

    if (lane == 0) {
      const float fg = sigmoid_f(A0 + bias[0]);
      const float ig = sigmoid_f(A1 + bias[1]);
      const float gg = tanh_f(A2 + bias[2]);
      const float og = sigmoid_f(A3 + bias[3]);
      creg = fg * creg + ig * gg;
      const float hn = og * tanh_f(creg);
      hout[wv] = hn;                          // collect for coalesced publish
      if (t == T_STEPS - 1) {
        out[(size_t)T_STEPS * NCH + j]       = hn;     // final h
        out[(size_t)T_STEPS * NCH + HID + j] = creg;   // final c
      }
    }
    __syncthreads();   // hout[] complete

    // ---- coalesced publish: ONE 64B line store, SYSTEM scope (R21) ----
    if (wv == 0 && lane < NEUR_PER_WG) {
      const unsigned long long pk =
          ((unsigned long long)__float_as_uint(hout[lane]) << 32) |
          (unsigned long long)(unsigned)(t + 1);
      st_sys64(&hbuf[(size_t)((t + 1) & 1) * HID +
                     (size_t)blockIdx.x * NEUR_PER_WG + lane], pk);
    }

    // ---- logits for step t-1 from already-staged h[t] (rides in wait slack) ----
    if (lcol >= 0 && t > 0) {
      const float4* hq4 = reinterpret_cast<const float4*>(&h_lds[bsel][0]);
      float sacc = 0.0f;
      #pragma unroll
      for (int u = 0; u < 8; ++u) {
        const float4 hv = hq4[u * 64 + lane];
        sacc = fmaf(wfc4[u].x, hv.x, sacc); sacc = fmaf(wfc4[u].y, hv.y, sacc);
        sacc = fmaf(wfc4[u].z, hv.z, sacc); sacc = fmaf(wfc4[u].w, hv.w, sacc);
      }
      const float S = wave_sum(sacc);
      if (lane == 0) out[(size_t)(t - 1) * NCH + lcol] = S + bfc_c;
    }
  }

  // ---- epilogue: stage h[T] (tag T, slot 0) and emit logits for t = T-1 ----
  {
    const unsigned long long* src = hbuf;  // T_STEPS & 1 == 0
    const unsigned ut = (unsigned)T_STEPS;
    unsigned long long v0 = ld_agent64(src + i0), v1 = ld_agent64(src + i1),
                       v2 = ld_agent64(src + i2), v3 = ld_agent64(src + i3);
    while (((unsigned)v0 != ut) | ((unsigned)v1 != ut) |
           ((unsigned)v2 != ut) | ((unsigned)v3 != ut)) {
      __builtin_amdgcn_s_sleep(2);
      if ((unsigned)v0 != ut) v0 = ld_agent64(src + i0);
      if ((unsigned)v1 != ut) v1 = ld_agent64(src + i1);
      if ((unsigned)v2 != ut) v2 = ld_agent64(src + i2);
      if ((unsigned)v3 != ut) v3 = ld_agent64(src + i3);
    }
    h_lds[0][i0] = __uint_as_float((unsigned)(v0 >> 32));
    h_lds[0][i1] = __uint_as_float((unsigned)(v1 >> 32));
    h_lds[0][i2] = __uint_as_float((unsigned)(v2 >> 32));
    h_lds[0][i3] = __uint_as_float((unsigned)(v3 >> 32));
    __syncthreads();
    if (lcol >= 0) {
      const float4* hq4 = reinterpret_cast<const float4*>(&h_lds[0][0]);
      float sacc = 0.0f;
      #pragma unroll
      for (int u = 0; u < 8; ++u) {
        const float4 hv = hq4[u * 64 + lane];
        sacc = fmaf(wfc4[u].x, hv.x, sacc); sacc = fmaf(wfc4[u].y, hv.y, sacc);
        sacc = fmaf(wfc4[u].z, hv.z, sacc); sacc = fmaf(wfc4[u].w, hv.w, sacc);
      }
      const float S = wave_sum(sacc);
      if (lane == 0) out[(size_t)(T_STEPS - 1) * NCH + lcol] = S + bfc_c;
    }
  }
}

extern "C" void kernel_launch(void* const* d_in, const int* in_sizes, int n_in,
                              void* d_out, int out_size, void* d_ws, size_t ws_size,
                              hipStream_t stream) {
  (void)in_sizes; (void)n_in; (void)out_size; (void)ws_size;
  const int* seq     = (const int*)d_in[0];
  const float* emb   = (const float*)d_in[1];
  const float* Wf    = (const float*)d_in[2];
  const float* bfv   = (const float*)d_in[3];
  const float* Wi    = (const float*)d_in[4];
  const float* biv   = (const float*)d_in[5];
  const float* Wg    = (const float*)d_in[6];
  const float* bgv   = (const float*)d_in[7];
  const float* Wo    = (const float*)d_in[8];
  const float* bov   = (const float*)d_in[9];
  const float* Wfc   = (const float*)d_in[10];
  const float* bfc   = (const float*)d_in[11];
  float* out         = (float*)d_out;
  unsigned long long* hbuf = (unsigned long long*)d_ws;   // 2*HID*8 = 32 KB

  hipMemsetAsync(d_ws, 0, 2 * HID * sizeof(unsigned long long), stream);

  void* args[] = {
    (void*)&seq, (void*)&emb,
    (void*)&Wf, (void*)&bfv, (void*)&Wi, (void*)&biv,
    (void*)&Wg, (void*)&bgv, (void*)&Wo, (void*)&bov,
    (void*)&Wfc, (void*)&bfc,
    (void*)&hbuf, (void*)&out
  };
  hipLaunchCooperativeKernel((const void*)lstm_persist, dim3(NBLK), dim3(TPB),
                             args, 0, stream);
}